// Round 2
// baseline (1526.643 us; speedup 1.0000x reference)
//
#include <hip/hip_runtime.h>
#include <cstdint>

typedef __attribute__((ext_vector_type(8))) short bf16x8;
typedef __attribute__((ext_vector_type(4))) float f32x4;

#define N_TOK    8192
#define DMODEL   1024
#define HDIM     4096
#define CAPACITY 2048

__device__ __forceinline__ unsigned short f2bf(float f) {
  unsigned u = __float_as_uint(f);
  u += 0x7FFFu + ((u >> 16) & 1u);
  return (unsigned short)(u >> 16);
}

// ---------------- router: logits -> top2 ----------------
__global__ void router_kernel(const float* __restrict__ x, const float* __restrict__ rw,
                              const float* __restrict__ rb, int4* __restrict__ recs) {
  int wave = threadIdx.x >> 6;
  int lane = threadIdx.x & 63;
  int tok = blockIdx.x * 4 + wave;
  const float* xr = x + (long)tok * DMODEL;
  float s[8];
#pragma unroll
  for (int e = 0; e < 8; e++) s[e] = 0.f;
  for (int ii = 0; ii < DMODEL / 64; ii++) {
    int k = lane + 64 * ii;
    float xv = xr[k];
    const float* wr = rw + k * 8;
    float4 a = *(const float4*)wr;
    float4 b = *(const float4*)(wr + 4);
    s[0] += xv * a.x; s[1] += xv * a.y; s[2] += xv * a.z; s[3] += xv * a.w;
    s[4] += xv * b.x; s[5] += xv * b.y; s[6] += xv * b.z; s[7] += xv * b.w;
  }
#pragma unroll
  for (int m = 1; m < 64; m <<= 1) {
#pragma unroll
    for (int e = 0; e < 8; e++) s[e] += __shfl_xor(s[e], m);
  }
  if (lane == 0) {
#pragma unroll
    for (int e = 0; e < 8; e++) s[e] += rb[e];
    int b0 = 0; float v0 = s[0];
#pragma unroll
    for (int e = 1; e < 8; e++) if (s[e] > v0) { v0 = s[e]; b0 = e; }
    int b1 = -1; float v1 = 0.f;
#pragma unroll
    for (int e = 0; e < 8; e++) {
      if (e == b0) continue;
      if (b1 < 0 || s[e] > v1) { v1 = s[e]; b1 = e; }
    }
    // softmax then renormalize over top2 == logistic on logit difference
    float t0 = 1.f / (1.f + expf(v1 - v0));
    float t1 = 1.f - t0;
    recs[tok] = make_int4(b0, b1, __float_as_int(t0), __float_as_int(t1));
  }
}

// ---------------- capacity assignment (single block) ----------------
__device__ __forceinline__ int bump16(uint4& v, int e) {
  unsigned sh = (e & 1) ? 16u : 0u;
  unsigned inc = 1u << sh;
  unsigned old;
  switch (e >> 1) {
    case 0: old = v.x; v.x += inc; break;
    case 1: old = v.y; v.y += inc; break;
    case 2: old = v.z; v.z += inc; break;
    default: old = v.w; v.w += inc; break;
  }
  return (int)((old >> sh) & 0xFFFFu);
}

__device__ __forceinline__ unsigned field16(uint4 v, int e) {
  unsigned w;
  switch (e >> 1) { case 0: w = v.x; break; case 1: w = v.y; break; case 2: w = v.z; break; default: w = v.w; break; }
  return (w >> ((e & 1) ? 16 : 0)) & 0xFFFFu;
}

__global__ void assign_kernel(const int4* __restrict__ recs, int* __restrict__ buf,
                              float* __restrict__ wc, int* __restrict__ cnt,
                              float* __restrict__ auxOut) {
  __shared__ uint4 sc[1024];
  __shared__ unsigned sco[1024];
  __shared__ float pnum[8];
  int tid = threadIdx.x;
  if (tid < 8) pnum[tid] = 0.f;
  int4 rc[8];
#pragma unroll
  for (int i = 0; i < 8; i++) {
    rc[i] = recs[tid * 8 + i];
    rc[i].x &= 7; rc[i].y &= 7;  // range guard: never scatter wild
  }
  uint4 c; c.x = c.y = c.z = c.w = 0u;
#pragma unroll
  for (int i = 0; i < 8; i++) { bump16(c, rc[i].x); bump16(c, rc[i].y); }
  sc[tid] = c;
  __syncthreads();
  for (int off = 1; off < 1024; off <<= 1) {
    uint4 v; v.x = v.y = v.z = v.w = 0u;
    if (tid >= off) v = sc[tid - off];
    __syncthreads();
    sc[tid].x += v.x; sc[tid].y += v.y; sc[tid].z += v.z; sc[tid].w += v.w;
    __syncthreads();
  }
  uint4 base; base.x = base.y = base.z = base.w = 0u;
  if (tid > 0) base = sc[tid - 1];
  uint4 totals = sc[1023];

  uint4 run = base;
  float wof[8];
  unsigned oc = 0;
#pragma unroll
  for (int i = 0; i < 8; i++) {
    int tk = tid * 8 + i;
    int e0 = rc[i].x, e1 = rc[i].y;
    float w0 = __int_as_float(rc[i].z);
    float w1 = __int_as_float(rc[i].w);
    float w = 0.f;
    int r0 = bump16(run, e0);
    if (r0 < CAPACITY) {
      buf[e0 * CAPACITY + r0] = tk;
      wc[e0 * CAPACITY + r0] = w0;
      atomicAdd(&pnum[e0], w0);
    } else w += w0;
    int r1 = bump16(run, e1);
    if (r1 < CAPACITY) {
      buf[e1 * CAPACITY + r1] = tk;
      wc[e1 * CAPACITY + r1] = w1;
      atomicAdd(&pnum[e1], w1);
    } else w += w1;
    wof[i] = w;
    if (w > 0.f) oc++;
  }
  sco[tid] = oc;
  __syncthreads();
  for (int off = 1; off < 1024; off <<= 1) {
    unsigned v = (tid >= off) ? sco[tid - off] : 0u;
    __syncthreads();
    sco[tid] += v;
    __syncthreads();
  }
  unsigned ob = (tid > 0) ? sco[tid - 1] : 0u;
  unsigned Ot = sco[1023];
#pragma unroll
  for (int i = 0; i < 8; i++) {
    if (wof[i] > 0.f) {
      unsigned slot = ob++;
      int ve = 8 + (int)(slot >> 11);
      buf[ve * CAPACITY + (int)(slot & 2047)] = tid * 8 + i;
      wc[ve * CAPACITY + (int)(slot & 2047)] = wof[i];
    }
  }
  __syncthreads();
  if (tid == 0) {
    float aux = 0.f;
#pragma unroll
    for (int e = 0; e < 8; e++) {
      int tot = (int)field16(totals, e);
      int c2 = tot < CAPACITY ? tot : CAPACITY;
      cnt[e] = c2;
      float f = (float)c2 / (float)N_TOK;
      float p = pnum[e] / (float)(c2 > 1 ? c2 : 1);
      aux += f * p;
    }
#pragma unroll
    for (int i = 0; i < 4; i++) {
      int c2 = (int)Ot - i * CAPACITY;
      c2 = c2 < 0 ? 0 : (c2 > CAPACITY ? CAPACITY : c2);
      cnt[8 + i] = c2;
    }
    auxOut[0] = 0.01f * 8.f * aux;
  }
}

// ---------------- fp32 -> bf16 transpose (weights), one matrix ----------------
__global__ __launch_bounds__(256) void transpose_kernel(const float* __restrict__ in,
                                                        unsigned short* __restrict__ out,
                                                        int R, int C) {
  int bx = blockIdx.x;
  int tr = bx / (C >> 6);
  int tc = bx % (C >> 6);
  int r0 = tr << 6, c0 = tc << 6;
  __shared__ float t[64][65];
  int row = threadIdx.x >> 4, cg = threadIdx.x & 15;
#pragma unroll
  for (int i = 0; i < 4; i++) {
    int r = row + 16 * i;
    float4 v = *(const float4*)(in + (long)(r0 + r) * C + c0 + cg * 4);
    t[r][cg * 4 + 0] = v.x; t[r][cg * 4 + 1] = v.y;
    t[r][cg * 4 + 2] = v.z; t[r][cg * 4 + 3] = v.w;
  }
  __syncthreads();
#pragma unroll
  for (int i = 0; i < 4; i++) {
    int oc = row + 16 * i;
    ushort4 o;
    o.x = f2bf(t[cg * 4 + 0][oc]);
    o.y = f2bf(t[cg * 4 + 1][oc]);
    o.z = f2bf(t[cg * 4 + 2][oc]);
    o.w = f2bf(t[cg * 4 + 3][oc]);
    *(ushort4*)(out + (long)(c0 + oc) * R + r0 + cg * 4) = o;
  }
}

// ---------------- GEMM1: h = relu(gather(x) @ W1 + b1), bf16 out ----------------
__global__ __launch_bounds__(256) void gemm1_kernel(
    const float* __restrict__ x, const int* __restrict__ buf,
    const int* __restrict__ cnt, const unsigned short* __restrict__ wt,
    const float* __restrict__ bias, unsigned short* __restrict__ h, int eIdx) {
  int bx = blockIdx.x;
  int mb = bx >> 5, nb = bx & 31;
  int m0 = mb * 128, n0 = nb * 128;
  if (m0 >= cnt[eIdx]) return;
  const int* bufe = buf + eIdx * CAPACITY;

  __shared__ unsigned short As[128 * 64];
  __shared__ unsigned short Bs[128 * 64];

  int tid = threadIdx.x;
  int rb8 = tid >> 3, ch = tid & 7;
  int tokA[4];
#pragma unroll
  for (int i = 0; i < 4; i++) tokA[i] = bufe[m0 + rb8 + 32 * i];

  int wave = tid >> 6, lane = tid & 63;
  int l15 = lane & 15, hi = lane >> 4;
  int mo = (wave >> 1) * 64, no = (wave & 1) * 64;

  f32x4 zero4 = {0.f, 0.f, 0.f, 0.f};
  f32x4 acc[4][4];
#pragma unroll
  for (int mi = 0; mi < 4; mi++)
#pragma unroll
    for (int ni = 0; ni < 4; ni++) acc[mi][ni] = zero4;

  for (int k0 = 0; k0 < DMODEL; k0 += 64) {
#pragma unroll
    for (int i = 0; i < 4; i++) {
      int r = rb8 + 32 * i;
      uint4 v; v.x = v.y = v.z = v.w = 0u;
      if ((unsigned)tokA[i] < (unsigned)N_TOK) {
        const float* src = x + (long)tokA[i] * DMODEL + k0 + ch * 8;
        float4 f0 = *(const float4*)src;
        float4 f1 = *(const float4*)(src + 4);
        v.x = (unsigned)f2bf(f0.x) | ((unsigned)f2bf(f0.y) << 16);
        v.y = (unsigned)f2bf(f0.z) | ((unsigned)f2bf(f0.w) << 16);
        v.z = (unsigned)f2bf(f1.x) | ((unsigned)f2bf(f1.y) << 16);
        v.w = (unsigned)f2bf(f1.z) | ((unsigned)f2bf(f1.w) << 16);
      }
      *(uint4*)&As[r * 64 + ((ch ^ (r & 7)) << 3)] = v;
      uint4 vb = *(const uint4*)(wt + (long)(n0 + r) * DMODEL + k0 + ch * 8);
      *(uint4*)&Bs[r * 64 + ((ch ^ (r & 7)) << 3)] = vb;
    }
    __syncthreads();
#pragma unroll
    for (int ks = 0; ks < 2; ks++) {
      bf16x8 af[4], bfr[4];
#pragma unroll
      for (int mi = 0; mi < 4; mi++) {
        int r = mo + mi * 16 + l15;
        af[mi] = *(bf16x8*)&As[r * 64 + (((ks * 4 + hi) ^ (r & 7)) << 3)];
      }
#pragma unroll
      for (int ni = 0; ni < 4; ni++) {
        int r = no + ni * 16 + l15;
        bfr[ni] = *(bf16x8*)&Bs[r * 64 + (((ks * 4 + hi) ^ (r & 7)) << 3)];
      }
#pragma unroll
      for (int mi = 0; mi < 4; mi++)
#pragma unroll
        for (int ni = 0; ni < 4; ni++)
          acc[mi][ni] = __builtin_amdgcn_mfma_f32_16x16x32_bf16(af[mi], bfr[ni], acc[mi][ni], 0, 0, 0);
    }
    __syncthreads();
  }
#pragma unroll
  for (int ni = 0; ni < 4; ni++) {
    int col = n0 + no + ni * 16 + l15;
    float bv = bias[col];
#pragma unroll
    for (int mi = 0; mi < 4; mi++) {
#pragma unroll
      for (int j = 0; j < 4; j++) {
        int mr = m0 + mo + mi * 16 + hi * 4 + j;
        float val = acc[mi][ni][j] + bv;
        val = val > 0.f ? val : 0.f;
        h[(long)mr * HDIM + col] = f2bf(val);
      }
    }
  }
}

// ---------------- GEMM2: out[tok] += wc * (h @ W2 + b2) ----------------
__global__ __launch_bounds__(256) void gemm2_kernel(
    const unsigned short* __restrict__ h, const unsigned short* __restrict__ wt,
    const float* __restrict__ bias, const int* __restrict__ buf,
    const float* __restrict__ wc, const int* __restrict__ cnt,
    float* __restrict__ out, int eIdx) {
  int bx = blockIdx.x;
  int mb = bx >> 3, nb = bx & 7;
  int m0 = mb * 128, n0 = nb * 128;
  if (m0 >= cnt[eIdx]) return;
  const int* bufe = buf + eIdx * CAPACITY;
  const float* wce = wc + eIdx * CAPACITY;

  __shared__ unsigned short As[128 * 64];
  __shared__ unsigned short Bs[128 * 64];

  int tid = threadIdx.x;
  int rb8 = tid >> 3, ch = tid & 7;
  int wave = tid >> 6, lane = tid & 63;
  int l15 = lane & 15, hi = lane >> 4;
  int mo = (wave >> 1) * 64, no = (wave & 1) * 64;

  f32x4 zero4 = {0.f, 0.f, 0.f, 0.f};
  f32x4 acc[4][4];
#pragma unroll
  for (int mi = 0; mi < 4; mi++)
#pragma unroll
    for (int ni = 0; ni < 4; ni++) acc[mi][ni] = zero4;

  for (int k0 = 0; k0 < HDIM; k0 += 64) {
#pragma unroll
    for (int i = 0; i < 4; i++) {
      int r = rb8 + 32 * i;
      uint4 va = *(const uint4*)(h + (long)(m0 + r) * HDIM + k0 + ch * 8);
      *(uint4*)&As[r * 64 + ((ch ^ (r & 7)) << 3)] = va;
      uint4 vb = *(const uint4*)(wt + (long)(n0 + r) * HDIM + k0 + ch * 8);
      *(uint4*)&Bs[r * 64 + ((ch ^ (r & 7)) << 3)] = vb;
    }
    __syncthreads();
#pragma unroll
    for (int ks = 0; ks < 2; ks++) {
      bf16x8 af[4], bfr[4];
#pragma unroll
      for (int mi = 0; mi < 4; mi++) {
        int r = mo + mi * 16 + l15;
        af[mi] = *(bf16x8*)&As[r * 64 + (((ks * 4 + hi) ^ (r & 7)) << 3)];
      }
#pragma unroll
      for (int ni = 0; ni < 4; ni++) {
        int r = no + ni * 16 + l15;
        bfr[ni] = *(bf16x8*)&Bs[r * 64 + (((ks * 4 + hi) ^ (r & 7)) << 3)];
      }
#pragma unroll
      for (int mi = 0; mi < 4; mi++)
#pragma unroll
        for (int ni = 0; ni < 4; ni++)
          acc[mi][ni] = __builtin_amdgcn_mfma_f32_16x16x32_bf16(af[mi], bfr[ni], acc[mi][ni], 0, 0, 0);
    }
    __syncthreads();
  }
#pragma unroll
  for (int mi = 0; mi < 4; mi++) {
#pragma unroll
    for (int j = 0; j < 4; j++) {
      int m = m0 + mo + mi * 16 + hi * 4 + j;
      int t = bufe[m];
      if ((unsigned)t >= (unsigned)N_TOK) continue;
      float wv = wce[m];
      float* orow = out + (long)t * DMODEL;
#pragma unroll
      for (int ni = 0; ni < 4; ni++) {
        int col = n0 + no + ni * 16 + l15;
        float val = wv * (acc[mi][ni][j] + bias[col]);
        atomicAdd(orow + col, val);
      }
    }
  }
}

// ---------------- host ----------------
extern "C" void kernel_launch(void* const* d_in, const int* in_sizes, int n_in,
                              void* d_out, int out_size, void* d_ws, size_t ws_size,
                              hipStream_t stream) {
  const float* x   = (const float*)d_in[0];
  const float* rw  = (const float*)d_in[1];
  const float* rb  = (const float*)d_in[2];
  const float* w1  = (const float*)d_in[3];
  const float* b1  = (const float*)d_in[4];
  const float* w2  = (const float*)d_in[5];
  const float* b2  = (const float*)d_in[6];
  const float* ow1 = (const float*)d_in[7];
  const float* ob1 = (const float*)d_in[8];
  const float* ow2 = (const float*)d_in[9];
  const float* ob2 = (const float*)d_in[10];
  float* out = (float*)d_out;

  // Workspace layout — small control arrays FIRST (lowest offsets), 33 MB total.
  char* ws = (char*)d_ws;
  int4* recs = (int4*)(ws);                                //       0 .. 131072
  int*  buf  = (int*)(ws + 131072);                        //  131072 .. 229376
  float* wcp = (float*)(ws + 229376);                      //  229376 .. 327680
  int*  cnt  = (int*)(ws + 327680);                        //  327680 .. 327744
  unsigned short* wt1 = (unsigned short*)(ws + 1048576);   //     1MB .. 9MB
  unsigned short* wt2 = (unsigned short*)(ws + 9437184);   //     9MB .. 17MB
  unsigned short* h   = (unsigned short*)(ws + 17825792);  //    17MB .. 33MB

  hipMemsetAsync(d_out, 0, (size_t)out_size * sizeof(float), stream);
  hipMemsetAsync(buf, 0xFF, 12 * CAPACITY * sizeof(int), stream);
  hipMemsetAsync(wcp, 0, 12 * CAPACITY * sizeof(float), stream);

  router_kernel<<<2048, 256, 0, stream>>>(x, rw, rb, recs);
  assign_kernel<<<1, 1024, 0, stream>>>(recs, buf, wcp, cnt, out + (long)N_TOK * DMODEL);

  for (int e = 0; e < 12; e++) {
    const float *bias1, *bias2;
    if (e < 8) {
      transpose_kernel<<<16 * 64, 256, 0, stream>>>(w1 + (long)e * DMODEL * HDIM, wt1, DMODEL, HDIM);
      transpose_kernel<<<64 * 16, 256, 0, stream>>>(w2 + (long)e * HDIM * DMODEL, wt2, HDIM, DMODEL);
      bias1 = b1 + (long)e * HDIM;
      bias2 = b2 + (long)e * DMODEL;
    } else {
      if (e == 8) {
        transpose_kernel<<<16 * 64, 256, 0, stream>>>(ow1, wt1, DMODEL, HDIM);
        transpose_kernel<<<64 * 16, 256, 0, stream>>>(ow2, wt2, HDIM, DMODEL);
      }
      bias1 = ob1;
      bias2 = ob2;
    }
    gemm1_kernel<<<16 * 32, 256, 0, stream>>>(x, buf, cnt, wt1, bias1, h, e);
    gemm2_kernel<<<16 * 8, 256, 0, stream>>>(h, wt2, bias2, buf, wcp, cnt, out, e);
  }
}

// Round 3
// 906.392 us; speedup vs baseline: 1.6843x; 1.6843x over previous
//
#include <hip/hip_runtime.h>
#include <cstdint>

typedef __attribute__((ext_vector_type(8))) short bf16x8;
typedef __attribute__((ext_vector_type(4))) float f32x4;

#define N_TOK    8192
#define DMODEL   1024
#define HDIM     4096
#define CAPACITY 2048

__device__ __forceinline__ unsigned short f2bf(float f) {
  unsigned u = __float_as_uint(f);
  u += 0x7FFFu + ((u >> 16) & 1u);
  return (unsigned short)(u >> 16);
}

__device__ __forceinline__ unsigned pack2(float a, float b) {
  return (unsigned)f2bf(a) | ((unsigned)f2bf(b) << 16);
}

// ---------------- router: logits -> top2 ----------------
__global__ void router_kernel(const float* __restrict__ x, const float* __restrict__ rw,
                              const float* __restrict__ rb, int4* __restrict__ recs) {
  int wave = threadIdx.x >> 6;
  int lane = threadIdx.x & 63;
  int tok = blockIdx.x * 4 + wave;
  const float* xr = x + (long)tok * DMODEL;
  float s[8];
#pragma unroll
  for (int e = 0; e < 8; e++) s[e] = 0.f;
  for (int ii = 0; ii < DMODEL / 64; ii++) {
    int k = lane + 64 * ii;
    float xv = xr[k];
    const float* wr = rw + k * 8;
    float4 a = *(const float4*)wr;
    float4 b = *(const float4*)(wr + 4);
    s[0] += xv * a.x; s[1] += xv * a.y; s[2] += xv * a.z; s[3] += xv * a.w;
    s[4] += xv * b.x; s[5] += xv * b.y; s[6] += xv * b.z; s[7] += xv * b.w;
  }
#pragma unroll
  for (int m = 1; m < 64; m <<= 1) {
#pragma unroll
    for (int e = 0; e < 8; e++) s[e] += __shfl_xor(s[e], m);
  }
  if (lane == 0) {
#pragma unroll
    for (int e = 0; e < 8; e++) s[e] += rb[e];
    int b0 = 0; float v0 = s[0];
#pragma unroll
    for (int e = 1; e < 8; e++) if (s[e] > v0) { v0 = s[e]; b0 = e; }
    int b1 = -1; float v1 = 0.f;
#pragma unroll
    for (int e = 0; e < 8; e++) {
      if (e == b0) continue;
      if (b1 < 0 || s[e] > v1) { v1 = s[e]; b1 = e; }
    }
    float t0 = 1.f / (1.f + expf(v1 - v0));
    float t1 = 1.f - t0;
    recs[tok] = make_int4(b0, b1, __float_as_int(t0), __float_as_int(t1));
  }
}

// ---------------- capacity assignment (single block) ----------------
__device__ __forceinline__ int bump16(uint4& v, int e) {
  unsigned sh = (e & 1) ? 16u : 0u;
  unsigned inc = 1u << sh;
  unsigned old;
  switch (e >> 1) {
    case 0: old = v.x; v.x += inc; break;
    case 1: old = v.y; v.y += inc; break;
    case 2: old = v.z; v.z += inc; break;
    default: old = v.w; v.w += inc; break;
  }
  return (int)((old >> sh) & 0xFFFFu);
}

__device__ __forceinline__ unsigned field16(uint4 v, int e) {
  unsigned w;
  switch (e >> 1) { case 0: w = v.x; break; case 1: w = v.y; break; case 2: w = v.z; break; default: w = v.w; break; }
  return (w >> ((e & 1) ? 16 : 0)) & 0xFFFFu;
}

__global__ void assign_kernel(const int4* __restrict__ recs, int* __restrict__ buf,
                              float* __restrict__ wc, int* __restrict__ cnt,
                              float* __restrict__ auxOut) {
  __shared__ uint4 sc[1024];
  __shared__ unsigned sco[1024];
  __shared__ float pnum[8];
  int tid = threadIdx.x;
  if (tid < 8) pnum[tid] = 0.f;
  int4 rc[8];
#pragma unroll
  for (int i = 0; i < 8; i++) {
    rc[i] = recs[tid * 8 + i];
    rc[i].x &= 7; rc[i].y &= 7;
  }
  uint4 c; c.x = c.y = c.z = c.w = 0u;
#pragma unroll
  for (int i = 0; i < 8; i++) { bump16(c, rc[i].x); bump16(c, rc[i].y); }
  sc[tid] = c;
  __syncthreads();
  for (int off = 1; off < 1024; off <<= 1) {
    uint4 v; v.x = v.y = v.z = v.w = 0u;
    if (tid >= off) v = sc[tid - off];
    __syncthreads();
    sc[tid].x += v.x; sc[tid].y += v.y; sc[tid].z += v.z; sc[tid].w += v.w;
    __syncthreads();
  }
  uint4 base; base.x = base.y = base.z = base.w = 0u;
  if (tid > 0) base = sc[tid - 1];
  uint4 totals = sc[1023];

  uint4 run = base;
  float wof[8];
  unsigned oc = 0;
#pragma unroll
  for (int i = 0; i < 8; i++) {
    int tk = tid * 8 + i;
    int e0 = rc[i].x, e1 = rc[i].y;
    float w0 = __int_as_float(rc[i].z);
    float w1 = __int_as_float(rc[i].w);
    float w = 0.f;
    int r0 = bump16(run, e0);
    if (r0 < CAPACITY) {
      buf[e0 * CAPACITY + r0] = tk;
      wc[e0 * CAPACITY + r0] = w0;
      atomicAdd(&pnum[e0], w0);
    } else w += w0;
    int r1 = bump16(run, e1);
    if (r1 < CAPACITY) {
      buf[e1 * CAPACITY + r1] = tk;
      wc[e1 * CAPACITY + r1] = w1;
      atomicAdd(&pnum[e1], w1);
    } else w += w1;
    wof[i] = w;
    if (w > 0.f) oc++;
  }
  sco[tid] = oc;
  __syncthreads();
  for (int off = 1; off < 1024; off <<= 1) {
    unsigned v = (tid >= off) ? sco[tid - off] : 0u;
    __syncthreads();
    sco[tid] += v;
    __syncthreads();
  }
  unsigned ob = (tid > 0) ? sco[tid - 1] : 0u;
  unsigned Ot = sco[1023];
#pragma unroll
  for (int i = 0; i < 8; i++) {
    if (wof[i] > 0.f) {
      unsigned slot = ob++;
      int ve = 8 + (int)(slot >> 11);
      buf[ve * CAPACITY + (int)(slot & 2047)] = tid * 8 + i;
      wc[ve * CAPACITY + (int)(slot & 2047)] = wof[i];
    }
  }
  __syncthreads();
  if (tid == 0) {
    float aux = 0.f;
#pragma unroll
    for (int e = 0; e < 8; e++) {
      int tot = (int)field16(totals, e);
      int c2 = tot < CAPACITY ? tot : CAPACITY;
      cnt[e] = c2;
      float f = (float)c2 / (float)N_TOK;
      float p = pnum[e] / (float)(c2 > 1 ? c2 : 1);
      aux += f * p;
    }
#pragma unroll
    for (int i = 0; i < 4; i++) {
      int c2 = (int)Ot - i * CAPACITY;
      c2 = c2 < 0 ? 0 : (c2 > CAPACITY ? CAPACITY : c2);
      cnt[8 + i] = c2;
    }
    auxOut[0] = 0.01f * 8.f * aux;
  }
}

// ---------------- fp32 -> bf16 transpose of TWO matrices in one dispatch ----------------
__global__ __launch_bounds__(256) void transpose2_kernel(
    const float* __restrict__ inA, unsigned short* __restrict__ outA, int RA, int CA, int tilesA,
    const float* __restrict__ inB, unsigned short* __restrict__ outB, int RB, int CB) {
  int bx = blockIdx.x;
  const float* in; unsigned short* out; int R, C, t;
  if (bx < tilesA) { in = inA; out = outA; R = RA; C = CA; t = bx; }
  else             { in = inB; out = outB; R = RB; C = CB; t = bx - tilesA; }
  int tr = t / (C >> 6);
  int tc = t % (C >> 6);
  int r0 = tr << 6, c0 = tc << 6;
  __shared__ float tl[64][65];
  int row = threadIdx.x >> 4, cg = threadIdx.x & 15;
#pragma unroll
  for (int i = 0; i < 4; i++) {
    int r = row + 16 * i;
    float4 v = *(const float4*)(in + (long)(r0 + r) * C + c0 + cg * 4);
    tl[r][cg * 4 + 0] = v.x; tl[r][cg * 4 + 1] = v.y;
    tl[r][cg * 4 + 2] = v.z; tl[r][cg * 4 + 3] = v.w;
  }
  __syncthreads();
#pragma unroll
  for (int i = 0; i < 4; i++) {
    int oc = row + 16 * i;
    ushort4 o;
    o.x = f2bf(tl[cg * 4 + 0][oc]);
    o.y = f2bf(tl[cg * 4 + 1][oc]);
    o.z = f2bf(tl[cg * 4 + 2][oc]);
    o.w = f2bf(tl[cg * 4 + 3][oc]);
    *(ushort4*)(out + (long)(c0 + oc) * R + r0 + cg * 4) = o;
  }
}

// ---------------- GEMM1: h = relu(gather(x) @ W1 + b1), 64x128 tiles ----------------
__global__ __launch_bounds__(256) void gemm1_kernel(
    const float* __restrict__ x, const int* __restrict__ buf,
    const int* __restrict__ cnt, const unsigned short* __restrict__ wt,
    const float* __restrict__ bias, unsigned short* __restrict__ h, int eIdx) {
  int bx = blockIdx.x;
  int id = (bx & 7) * 128 + (bx >> 3);   // XCD-aware bijective swizzle (nwg=1024)
  int mb = id >> 5, nb = id & 31;        // 32 x 32
  int m0 = mb * 64, n0 = nb * 128;
  if (m0 >= cnt[eIdx]) return;
  const int* bufe = buf + eIdx * CAPACITY;

  __shared__ unsigned short As[64 * 64];
  __shared__ unsigned short Bs[128 * 64];

  int tid = threadIdx.x;
  // A staging: 64 rows x 64 k, 16 f32 per thread (2 chunk16 units)
  int arow = tid >> 2;
  int akc  = (tid & 3) << 1;             // chunk idx (8-el units): 0,2,4,6
  int tokA = bufe[m0 + arow];
  const float* asrc = nullptr;
  if ((unsigned)tokA < (unsigned)N_TOK) asrc = x + (long)tokA * DMODEL + (akc << 3);
  int aswz0 = arow * 64 + ((akc ^ (arow & 7)) << 3);
  int aswz1 = arow * 64 + (((akc + 1) ^ (arow & 7)) << 3);

  // B staging: 128 rows x 64 k, 32 bf16 per thread (4 chunk16 units)
  int brow = tid >> 1;
  int bkc  = (tid & 1) << 2;             // 0 or 4
  const unsigned short* bsrc = wt + (long)(n0 + brow) * DMODEL + (bkc << 3);

  int wave = tid >> 6, lane = tid & 63;
  int l15 = lane & 15, hi = lane >> 4;
  int mo = (wave >> 1) * 32, no = (wave & 1) * 64;

  f32x4 zero4 = {0.f, 0.f, 0.f, 0.f};
  f32x4 acc[2][4];
#pragma unroll
  for (int mi = 0; mi < 2; mi++)
#pragma unroll
    for (int ni = 0; ni < 4; ni++) acc[mi][ni] = zero4;

  for (int k0 = 0; k0 < DMODEL; k0 += 64) {
    uint4 pa0, pa1;
    pa0.x = pa0.y = pa0.z = pa0.w = 0u; pa1 = pa0;
    if (asrc) {
      float4 f0 = *(const float4*)(asrc + k0);
      float4 f1 = *(const float4*)(asrc + k0 + 4);
      float4 f2 = *(const float4*)(asrc + k0 + 8);
      float4 f3 = *(const float4*)(asrc + k0 + 12);
      pa0.x = pack2(f0.x, f0.y); pa0.y = pack2(f0.z, f0.w);
      pa0.z = pack2(f1.x, f1.y); pa0.w = pack2(f1.z, f1.w);
      pa1.x = pack2(f2.x, f2.y); pa1.y = pack2(f2.z, f2.w);
      pa1.z = pack2(f3.x, f3.y); pa1.w = pack2(f3.z, f3.w);
    }
    uint4 vb[4];
#pragma unroll
    for (int i = 0; i < 4; i++) vb[i] = *(const uint4*)(bsrc + k0 + i * 8);
    *(uint4*)&As[aswz0] = pa0;
    *(uint4*)&As[aswz1] = pa1;
#pragma unroll
    for (int i = 0; i < 4; i++)
      *(uint4*)&Bs[brow * 64 + (((bkc + i) ^ (brow & 7)) << 3)] = vb[i];
    __syncthreads();
#pragma unroll
    for (int ks = 0; ks < 2; ks++) {
      bf16x8 af[2], bfr[4];
#pragma unroll
      for (int mi = 0; mi < 2; mi++) {
        int r = mo + mi * 16 + l15;
        af[mi] = *(bf16x8*)&As[r * 64 + (((ks * 4 + hi) ^ (r & 7)) << 3)];
      }
#pragma unroll
      for (int ni = 0; ni < 4; ni++) {
        int r = no + ni * 16 + l15;
        bfr[ni] = *(bf16x8*)&Bs[r * 64 + (((ks * 4 + hi) ^ (r & 7)) << 3)];
      }
#pragma unroll
      for (int mi = 0; mi < 2; mi++)
#pragma unroll
        for (int ni = 0; ni < 4; ni++)
          acc[mi][ni] = __builtin_amdgcn_mfma_f32_16x16x32_bf16(af[mi], bfr[ni], acc[mi][ni], 0, 0, 0);
    }
    __syncthreads();
  }
#pragma unroll
  for (int ni = 0; ni < 4; ni++) {
    int col = n0 + no + ni * 16 + l15;
    float bv = bias[col];
#pragma unroll
    for (int mi = 0; mi < 2; mi++) {
#pragma unroll
      for (int j = 0; j < 4; j++) {
        int mr = m0 + mo + mi * 16 + hi * 4 + j;
        float val = acc[mi][ni][j] + bv;
        val = val > 0.f ? val : 0.f;
        h[(long)mr * HDIM + col] = f2bf(val);
      }
    }
  }
}

// ---------------- GEMM2: out[tok] += wc * (h @ W2 + b2), K-split x4 ----------------
__global__ __launch_bounds__(256) void gemm2_kernel(
    const unsigned short* __restrict__ h, const unsigned short* __restrict__ wt,
    const float* __restrict__ bias, const int* __restrict__ buf,
    const float* __restrict__ wc, const int* __restrict__ cnt,
    float* __restrict__ out, int eIdx) {
  int bx = blockIdx.x;
  int id = (bx & 7) * 64 + (bx >> 3);    // XCD-aware bijective swizzle (nwg=512)
  int kc = id >> 7;
  int rem = id & 127;
  int mb = rem >> 3, nb = rem & 7;
  int m0 = mb * 128, n0 = nb * 128;
  if (m0 >= cnt[eIdx]) return;
  const int* bufe = buf + eIdx * CAPACITY;
  const float* wce = wc + eIdx * CAPACITY;
  int kbase = kc << 10;

  __shared__ unsigned short As[128 * 64];
  __shared__ unsigned short Bs[128 * 64];

  int tid = threadIdx.x;
  int rb8 = tid >> 3, ch = tid & 7;
  int wave = tid >> 6, lane = tid & 63;
  int l15 = lane & 15, hi = lane >> 4;
  int mo = (wave >> 1) * 64, no = (wave & 1) * 64;

  f32x4 zero4 = {0.f, 0.f, 0.f, 0.f};
  f32x4 acc[4][4];
#pragma unroll
  for (int mi = 0; mi < 4; mi++)
#pragma unroll
    for (int ni = 0; ni < 4; ni++) acc[mi][ni] = zero4;

  for (int k0 = kbase; k0 < kbase + 1024; k0 += 64) {
#pragma unroll
    for (int i = 0; i < 4; i++) {
      int r = rb8 + 32 * i;
      uint4 va = *(const uint4*)(h + (long)(m0 + r) * HDIM + k0 + ch * 8);
      *(uint4*)&As[r * 64 + ((ch ^ (r & 7)) << 3)] = va;
      uint4 vb = *(const uint4*)(wt + (long)(n0 + r) * HDIM + k0 + ch * 8);
      *(uint4*)&Bs[r * 64 + ((ch ^ (r & 7)) << 3)] = vb;
    }
    __syncthreads();
#pragma unroll
    for (int ks = 0; ks < 2; ks++) {
      bf16x8 af[4], bfr[4];
#pragma unroll
      for (int mi = 0; mi < 4; mi++) {
        int r = mo + mi * 16 + l15;
        af[mi] = *(bf16x8*)&As[r * 64 + (((ks * 4 + hi) ^ (r & 7)) << 3)];
      }
#pragma unroll
      for (int ni = 0; ni < 4; ni++) {
        int r = no + ni * 16 + l15;
        bfr[ni] = *(bf16x8*)&Bs[r * 64 + (((ks * 4 + hi) ^ (r & 7)) << 3)];
      }
#pragma unroll
      for (int mi = 0; mi < 4; mi++)
#pragma unroll
        for (int ni = 0; ni < 4; ni++)
          acc[mi][ni] = __builtin_amdgcn_mfma_f32_16x16x32_bf16(af[mi], bfr[ni], acc[mi][ni], 0, 0, 0);
    }
    __syncthreads();
  }
  float bcol[4];
#pragma unroll
  for (int ni = 0; ni < 4; ni++)
    bcol[ni] = (kc == 0) ? bias[n0 + no + ni * 16 + l15] : 0.f;
#pragma unroll
  for (int mi = 0; mi < 4; mi++) {
#pragma unroll
    for (int j = 0; j < 4; j++) {
      int m = m0 + mo + mi * 16 + hi * 4 + j;
      int t = bufe[m];
      if ((unsigned)t >= (unsigned)N_TOK) continue;
      float wv = wce[m];
      float* orow = out + (long)t * DMODEL;
#pragma unroll
      for (int ni = 0; ni < 4; ni++) {
        int col = n0 + no + ni * 16 + l15;
        float val = wv * (acc[mi][ni][j] + bcol[ni]);
        atomicAdd(orow + col, val);
      }
    }
  }
}

// ---------------- host ----------------
extern "C" void kernel_launch(void* const* d_in, const int* in_sizes, int n_in,
                              void* d_out, int out_size, void* d_ws, size_t ws_size,
                              hipStream_t stream) {
  const float* x   = (const float*)d_in[0];
  const float* rw  = (const float*)d_in[1];
  const float* rb  = (const float*)d_in[2];
  const float* w1  = (const float*)d_in[3];
  const float* b1  = (const float*)d_in[4];
  const float* w2  = (const float*)d_in[5];
  const float* b2  = (const float*)d_in[6];
  const float* ow1 = (const float*)d_in[7];
  const float* ob1 = (const float*)d_in[8];
  const float* ow2 = (const float*)d_in[9];
  const float* ob2 = (const float*)d_in[10];
  float* out = (float*)d_out;

  // Workspace layout — 33 MB total (ws_size known-good >= 33 MB, < 84 MB).
  char* ws = (char*)d_ws;
  int4* recs = (int4*)(ws);
  int*  buf  = (int*)(ws + 131072);
  float* wcp = (float*)(ws + 229376);
  int*  cnt  = (int*)(ws + 327680);
  unsigned short* wt1 = (unsigned short*)(ws + 1048576);
  unsigned short* wt2 = (unsigned short*)(ws + 9437184);
  unsigned short* h   = (unsigned short*)(ws + 17825792);

  hipMemsetAsync(d_out, 0, (size_t)out_size * sizeof(float), stream);
  hipMemsetAsync(buf, 0xFF, 12 * CAPACITY * sizeof(int), stream);
  hipMemsetAsync(wcp, 0, 12 * CAPACITY * sizeof(float), stream);

  router_kernel<<<2048, 256, 0, stream>>>(x, rw, rb, recs);
  assign_kernel<<<1, 1024, 0, stream>>>(recs, buf, wcp, cnt, out + (long)N_TOK * DMODEL);

  for (int e = 0; e < 12; e++) {
    const float *bias1, *bias2;
    if (e < 8) {
      transpose2_kernel<<<2048, 256, 0, stream>>>(
          w1 + (long)e * DMODEL * HDIM, wt1, DMODEL, HDIM, 1024,
          w2 + (long)e * HDIM * DMODEL, wt2, HDIM, DMODEL);
      bias1 = b1 + (long)e * HDIM;
      bias2 = b2 + (long)e * DMODEL;
    } else {
      if (e == 8) {
        transpose2_kernel<<<2048, 256, 0, stream>>>(
            ow1, wt1, DMODEL, HDIM, 1024,
            ow2, wt2, HDIM, DMODEL);
      }
      bias1 = ob1;
      bias2 = ob2;
    }
    gemm1_kernel<<<1024, 256, 0, stream>>>(x, buf, cnt, wt1, bias1, h, e);
    gemm2_kernel<<<512, 256, 0, stream>>>(h, wt2, bias2, buf, wcp, cnt, out, e);
  }
}